// Round 7
// baseline (1194.173 us; speedup 1.0000x reference)
//
#include <hip/hip_runtime.h>
#include <cmath>

#define DEV __device__ __forceinline__

constexpr int NA    = 32768;          // atoms
constexpr int M     = 12;             // neighbors
constexpr int ORIG  = 92;
constexpr int NBR   = 41;
constexpr int AF    = 64;
constexpr int C2    = 128;            // 2*AF
constexpr int HF    = 128;
constexpr int NCONV = 3;
constexpr int NM    = NA * M;         // 393216
constexpr int BB    = 1024;           // crystals
constexpr int TA    = 4;              // atoms per tile
constexpr int RT    = TA * M;         // 48 rows per tile
constexpr int NTILES = NA / TA;       // 8192
constexpr int GRID_CONV = 2048;
constexpr int WLD   = 132;            // W2t row stride (2-way banks only = free)
constexpr int ALD   = 44;             // A tile row stride (16B-aligned rows)

DEV float fsig(float x) { return __builtin_amdgcn_rcpf(1.f + __expf(-x)); }
DEV float fsp (float x) { return fmaxf(x, 0.f) + __logf(1.f + __expf(-fabsf(x))); }

DEV void fma4(float4& a, float s, const float4 w) {
    a.x = fmaf(s, w.x, a.x); a.y = fmaf(s, w.y, a.y);
    a.z = fmaf(s, w.z, a.z); a.w = fmaf(s, w.w, a.w);
}
DEV float comp4(const float4 v, int i) { return i == 0 ? v.x : i == 1 ? v.y : i == 2 ? v.z : v.w; }
DEV void add4(float4& a, const float4 b) { a.x += b.x; a.y += b.y; a.z += b.z; a.w += b.w; }
DEV void sqa4(float4& a, const float4 b) {
    a.x = fmaf(b.x, b.x, a.x); a.y = fmaf(b.y, b.y, a.y);
    a.z = fmaf(b.z, b.z, a.z); a.w = fmaf(b.w, b.w, a.w);
}
DEV float4 shxor(const float4 v, int m) {
    float4 r;
    r.x = __shfl_xor(v.x, m, 64); r.y = __shfl_xor(v.y, m, 64);
    r.z = __shfl_xor(v.z, m, 64); r.w = __shfl_xor(v.w, m, 64);
    return r;
}
DEV void bfly4(float4& v) {              // 4-way sum across lanes xor 16,32
    float4 t = shxor(v, 16); add4(v, t);
    t = shxor(v, 32); add4(v, t);
}
DEV unsigned bf16pair(float a, float b) {   // RNE pack: low=a, high=b
    unsigned ua = __float_as_uint(a), ub = __float_as_uint(b);
    ua += 0x7fffu + ((ua >> 16) & 1u);
    ub += 0x7fffu + ((ub >> 16) & 1u);
    return (ua >> 16) | (ub & 0xffff0000u);
}
DEV float4 up4(const uint2 q) {             // unpack 4 bf16 -> float4
    float4 r;
    r.x = __uint_as_float(q.x << 16);
    r.y = __uint_as_float(q.x & 0xffff0000u);
    r.z = __uint_as_float(q.y << 16);
    r.w = __uint_as_float(q.y & 0xffff0000u);
    return r;
}

// ---- spx: x-update (embed for layer0, softplus(x+bn2(summed)) otherwise)
//      fused with S = x@W[0:64]+b (fp32) and P = x@W[64:128] (packed bf16) ----
template<bool FIRST>
__global__ __launch_bounds__(256, 4)
void spx_kernel(const float* __restrict__ xin,
                const float* __restrict__ summed,
                const float* __restrict__ ss2,
                const float* __restrict__ atom_fea,
                const float* __restrict__ embW,
                const float* __restrict__ embb,
                const float* __restrict__ W,      // layer's conv_W (rows 0..127 used)
                const float* __restrict__ bias,   // layer's conv_b
                float* __restrict__ xout,
                float* __restrict__ S,
                unsigned* __restrict__ Pb)
{
    __shared__ float xs[16][AF];
    __shared__ float af[FIRST ? 16 * ORIG : 4];

    const int a0 = blockIdx.x * 16, tid = threadIdx.x;

    if (FIRST) {
        for (int i = tid; i < 16 * ORIG; i += 256) af[i] = atom_fea[(size_t)a0 * ORIG + i];
        __syncthreads();
        const int row = tid >> 4, c4 = (tid & 15) * 4;
        float4 acc = *(const float4*)(embb + c4);
        #pragma unroll 4
        for (int k = 0; k < ORIG; ++k)
            fma4(acc, af[row * ORIG + k], *(const float4*)(embW + k * AF + c4));
        *(float4*)&xs[row][c4] = acc;
        *(float4*)(xout + (size_t)(a0 + row) * AF + c4) = acc;
    } else {
        const int row = tid >> 4, c4 = (tid & 15) * 4;
        const size_t o = (size_t)(a0 + row) * AF + c4;
        const float4 xi = *(const float4*)(xin + o);
        const float4 sm = *(const float4*)(summed + o);
        const float4 sc = *(const float4*)(ss2 + c4);
        const float4 sh = *(const float4*)(ss2 + AF + c4);
        float4 ov;
        ov.x = fsp(xi.x + fmaf(sm.x, sc.x, sh.x));
        ov.y = fsp(xi.y + fmaf(sm.y, sc.y, sh.y));
        ov.z = fsp(xi.z + fmaf(sm.z, sc.z, sh.z));
        ov.w = fsp(xi.w + fmaf(sm.w, sc.w, sh.w));
        *(float4*)&xs[row][c4] = ov;
        *(float4*)(xout + o) = ov;
    }
    __syncthreads();

    // S/P GEMM: 32 col-threads (8 cols) x 8 row-threads (2 rows)
    const int cid = tid & 31, rid = tid >> 5;
    const int c0 = cid * 8, r0 = rid * 2;
    const bool isS = (c0 < 128);
    const int cc = c0 & 127;
    const float* Wb = W + (isS ? 0 : AF * C2) + cc;
    float4 a00, a01, a10, a11;
    if (isS) { a00 = *(const float4*)(bias + cc); a01 = *(const float4*)(bias + cc + 4); }
    else     { a00 = {0,0,0,0}; a01 = {0,0,0,0}; }
    a10 = a00; a11 = a01;
    for (int k = 0; k < AF; ++k) {
        const float4 w0 = *(const float4*)(Wb + k * C2);
        const float4 w1 = *(const float4*)(Wb + k * C2 + 4);
        const float x0 = xs[r0][k], x1 = xs[r0 + 1][k];
        fma4(a00, x0, w0); fma4(a01, x0, w1);
        fma4(a10, x1, w0); fma4(a11, x1, w1);
    }
    if (isS) {
        *(float4*)(S + (size_t)(a0 + r0) * C2 + cc)     = a00;
        *(float4*)(S + (size_t)(a0 + r0) * C2 + cc + 4) = a01;
        *(float4*)(S + (size_t)(a0 + r0 + 1) * C2 + cc)     = a10;
        *(float4*)(S + (size_t)(a0 + r0 + 1) * C2 + cc + 4) = a11;
    } else {
        uint4 u0, u1;
        u0.x = bf16pair(a00.x, a00.y); u0.y = bf16pair(a00.z, a00.w);
        u0.z = bf16pair(a01.x, a01.y); u0.w = bf16pair(a01.z, a01.w);
        u1.x = bf16pair(a10.x, a10.y); u1.y = bf16pair(a10.z, a10.w);
        u1.z = bf16pair(a11.x, a11.y); u1.w = bf16pair(a11.z, a11.w);
        *(uint4*)(Pb + (size_t)(a0 + r0) * 64 + cc / 2)     = u0;
        *(uint4*)(Pb + (size_t)(a0 + r0 + 1) * 64 + cc / 2) = u1;
    }
}

// ------- conv core: g[n,m] = S[n] + P[idx[n,m]] + nbr[n,m]@W2 ------------------
// Register-frugal pipeline (R6) + PINNED OCCUPANCY: amdgpu_waves_per_eu(4,4)
// gives the allocator a 128-VGPR budget (512/SIMD / 4 waves) so the ~115-reg
// live set fits without scratch spill (R4-R6's 600 MB WRITE_SIZE signature).
// MODE 0: per-column sum/sumsq of g (BN1 stats partials).
// MODE 1: BN1-apply + gate + sum over M -> summed; fused BN2 partial stats.
template<int MODE>
__global__ __attribute__((amdgpu_waves_per_eu(4, 4))) __launch_bounds__(256)
void conv6_kernel(const float* __restrict__ nbr_fea,
                  const int* __restrict__ idx,
                  const float* __restrict__ W2,
                  const float* __restrict__ S,
                  const unsigned* __restrict__ Pb,
                  const float* __restrict__ ss1,
                  float* __restrict__ P1s, float* __restrict__ P1q,
                  float* __restrict__ summed,
                  float* __restrict__ P2s, float* __restrict__ P2q)
{
    __shared__ float W2t[NBR * WLD];     // 21.6 KB
    __shared__ float sA[RT * ALD];       // 8.45 KB

    const int tid  = threadIdx.x;
    const int cid  = tid & 15;
    const int rid  = tid >> 4;
    const int cf   = cid * 4;            // filter col base; core col = cf + 64
    const int r0   = rid * 3;
    const int atom = tid >> 6;           // wave index == atom-in-tile

    for (int i = tid; i < NBR * 32; i += 256) {
        const int k = i >> 5, c4 = (i & 31) * 4;
        *(float4*)&W2t[k * WLD + c4] = *(const float4*)(W2 + k * C2 + c4);
    }

    // staging LDS offsets tile-invariant: element e -> sA[(e/41)*ALD + e%41]
    int soff[8];
    #pragma unroll
    for (int i = 0; i < 8; ++i) {
        const int e = tid + 256 * i;
        if (e < RT * NBR) {
            const int r = (int)(((unsigned)e * 102301u) >> 22);
            soff[i] = r * ALD + (e - r * NBR);
        } else soff[i] = -1;
    }

    float4 scf, scc, shf, shc;
    if (MODE == 1) {
        scf = *(const float4*)(ss1 + cf);        scc = *(const float4*)(ss1 + 64 + cf);
        shf = *(const float4*)(ss1 + C2 + cf);   shc = *(const float4*)(ss1 + C2 + 64 + cf);
    }

    const int stride = gridDim.x;
    int t = blockIdx.x;

    // prologue: first tile's idx + nbr loads
    float nb[8];
    int jn0, jn1, jn2;
    {
        const int n0 = t * TA;
        jn0 = idx[n0 * M + r0 + 0];
        jn1 = idx[n0 * M + r0 + 1];
        jn2 = idx[n0 * M + r0 + 2];
        const float* src = nbr_fea + (size_t)n0 * M * NBR;
        #pragma unroll
        for (int i = 0; i < 8; ++i) nb[i] = (soff[i] >= 0) ? src[tid + 256 * i] : 0.f;
    }

    float4 sum_f = {0,0,0,0}, sum_c = {0,0,0,0}, sq_f = {0,0,0,0}, sq_c = {0,0,0,0};
    float4 ts = {0,0,0,0}, tq = {0,0,0,0};   // MODE1 BN2 partials

    for (; t < NTILES; t += stride) {
        const int n0 = t * TA;
        const int tc = (t + stride < NTILES) ? (t + stride) : t;   // clamped next

        __syncthreads();                 // prev tile LDS fully consumed
        #pragma unroll
        for (int i = 0; i < 8; ++i) if (soff[i] >= 0) sA[soff[i]] = nb[i];
        __syncthreads();

        // far loads for CURRENT tile -- consumed after the GEMM (epilogue)
        const float4 svf = *(const float4*)(S + (size_t)(n0 + atom) * C2 + cf);
        const float4 svc = *(const float4*)(S + (size_t)(n0 + atom) * C2 + 64 + cf);
        const uint2 q0f = *(const uint2*)(Pb + (size_t)jn0 * 64 + 2 * cid);
        const uint2 q0c = *(const uint2*)(Pb + (size_t)jn0 * 64 + 32 + 2 * cid);
        const uint2 q1f = *(const uint2*)(Pb + (size_t)jn1 * 64 + 2 * cid);
        const uint2 q1c = *(const uint2*)(Pb + (size_t)jn1 * 64 + 32 + 2 * cid);
        const uint2 q2f = *(const uint2*)(Pb + (size_t)jn2 * 64 + 2 * cid);
        const uint2 q2c = *(const uint2*)(Pb + (size_t)jn2 * 64 + 32 + 2 * cid);

        // prefetch NEXT tile: idx (for next iter's gathers) + nbr staging regs
        {
            const int m0 = tc * TA;
            jn0 = idx[m0 * M + r0 + 0];
            jn1 = idx[m0 * M + r0 + 1];
            jn2 = idx[m0 * M + r0 + 2];
            const float* srcn = nbr_fea + (size_t)m0 * M * NBR;
            #pragma unroll
            for (int i = 0; i < 8; ++i) nb[i] = (soff[i] >= 0) ? srcn[tid + 256 * i] : 0.f;
        }

        // ---- E-GEMM from zero: nbr @ W2, 3 rows x (4+4) cols ----
        float4 ef0={0,0,0,0}, ec0={0,0,0,0}, ef1={0,0,0,0}, ec1={0,0,0,0}, ef2={0,0,0,0}, ec2={0,0,0,0};
        const float4* A0 = (const float4*)(sA + (r0 + 0) * ALD);
        const float4* A1 = (const float4*)(sA + (r0 + 1) * ALD);
        const float4* A2 = (const float4*)(sA + (r0 + 2) * ALD);
        #pragma unroll 2
        for (int k4 = 0; k4 < 10; ++k4) {
            const float4 a0 = A0[k4], a1 = A1[k4], a2 = A2[k4];
            #pragma unroll
            for (int kk = 0; kk < 4; ++kk) {
                const int k = 4 * k4 + kk;
                const float4 wf = *(const float4*)(W2t + k * WLD + cf);
                const float4 wc = *(const float4*)(W2t + k * WLD + 64 + cf);
                fma4(ef0, comp4(a0, kk), wf); fma4(ec0, comp4(a0, kk), wc);
                fma4(ef1, comp4(a1, kk), wf); fma4(ec1, comp4(a1, kk), wc);
                fma4(ef2, comp4(a2, kk), wf); fma4(ec2, comp4(a2, kk), wc);
            }
        }
        {   // k = 40
            const float4 wf = *(const float4*)(W2t + 40 * WLD + cf);
            const float4 wc = *(const float4*)(W2t + 40 * WLD + 64 + cf);
            const float a0s = sA[(r0 + 0) * ALD + 40];
            const float a1s = sA[(r0 + 1) * ALD + 40];
            const float a2s = sA[(r0 + 2) * ALD + 40];
            fma4(ef0, a0s, wf); fma4(ec0, a0s, wc);
            fma4(ef1, a1s, wf); fma4(ec1, a1s, wc);
            fma4(ef2, a2s, wf); fma4(ec2, a2s, wc);
        }

        // ---- epilogue: g = E + S + P[idx] (gathers have had the GEMM to land) ----
        add4(ef0, svf); add4(ef0, up4(q0f));  add4(ec0, svc); add4(ec0, up4(q0c));
        add4(ef1, svf); add4(ef1, up4(q1f));  add4(ec1, svc); add4(ec1, up4(q1c));
        add4(ef2, svf); add4(ef2, up4(q2f));  add4(ec2, svc); add4(ec2, up4(q2c));

        if (MODE == 0) {
            add4(sum_f, ef0); add4(sum_f, ef1); add4(sum_f, ef2);
            add4(sum_c, ec0); add4(sum_c, ec1); add4(sum_c, ec2);
            sqa4(sq_f, ef0);  sqa4(sq_f, ef1);  sqa4(sq_f, ef2);
            sqa4(sq_c, ec0);  sqa4(sq_c, ec1);  sqa4(sq_c, ec2);
        } else {
            float4 part = {0,0,0,0};
            #pragma unroll
            for (int j = 0; j < 3; ++j) {
                const float4 gf = (j == 0) ? ef0 : (j == 1) ? ef1 : ef2;
                const float4 gc = (j == 0) ? ec0 : (j == 1) ? ec1 : ec2;
                float4 nf, nc;
                nf.x = fmaf(gf.x, scf.x, shf.x); nf.y = fmaf(gf.y, scf.y, shf.y);
                nf.z = fmaf(gf.z, scf.z, shf.z); nf.w = fmaf(gf.w, scf.w, shf.w);
                nc.x = fmaf(gc.x, scc.x, shc.x); nc.y = fmaf(gc.y, scc.y, shc.y);
                nc.z = fmaf(gc.z, scc.z, shc.z); nc.w = fmaf(gc.w, scc.w, shc.w);
                part.x = fmaf(fsig(nf.x), fsp(nc.x), part.x);
                part.y = fmaf(fsig(nf.y), fsp(nc.y), part.y);
                part.z = fmaf(fsig(nf.z), fsp(nc.z), part.z);
                part.w = fmaf(fsig(nf.w), fsp(nc.w), part.w);
            }
            bfly4(part);
            if ((tid & 48) == 0) {
                *(float4*)(summed + (size_t)(n0 + atom) * AF + cf) = part;
                add4(ts, part);
                sqa4(tq, part);
            }
        }
    }

    if (MODE == 0) {   // block-level reduce of per-thread BN1 stats
        bfly4(sum_f); bfly4(sum_c); bfly4(sq_f); bfly4(sq_c);
        __syncthreads();                 // sA free (all tiles done)
        if ((tid & 48) == 0) {
            *(float4*)&sA[atom * C2 + cf]            = sum_f;
            *(float4*)&sA[atom * C2 + 64 + cf]       = sum_c;
            *(float4*)&sA[512 + atom * C2 + cf]      = sq_f;
            *(float4*)&sA[512 + atom * C2 + 64 + cf] = sq_c;
        }
        __syncthreads();
        if (tid < C2) {
            P1s[blockIdx.x * C2 + tid] = sA[tid] + sA[C2 + tid] + sA[2 * C2 + tid] + sA[3 * C2 + tid];
            P1q[blockIdx.x * C2 + tid] = sA[512 + tid] + sA[512 + C2 + tid]
                                       + sA[512 + 2 * C2 + tid] + sA[512 + 3 * C2 + tid];
        }
    } else {           // block-level reduce of BN2 partials
        __syncthreads();
        if ((tid & 48) == 0) {
            *(float4*)&sA[atom * AF + cf]       = ts;
            *(float4*)&sA[256 + atom * AF + cf] = tq;
        }
        __syncthreads();
        if (tid < AF) {
            P2s[blockIdx.x * AF + tid] = sA[tid] + sA[AF + tid] + sA[2 * AF + tid] + sA[3 * AF + tid];
            P2q[blockIdx.x * AF + tid] = sA[256 + tid] + sA[256 + AF + tid]
                                       + sA[256 + 2 * AF + tid] + sA[256 + 3 * AF + tid];
        }
    }
}

// ---------------- BN stats finalize: partials -> per-column scale/shift ----------
__global__ __launch_bounds__(256)
void bn_finalize(const float* __restrict__ Ps, const float* __restrict__ Pq,
                 int npart, int C, float invn,
                 const float* __restrict__ gamma, const float* __restrict__ beta,
                 float* __restrict__ ss)
{
    __shared__ float sd[256];
    const int c = blockIdx.x, tid = threadIdx.x;
    float s = 0.f;
    for (int j = tid; j < npart; j += 256) s += Ps[j * C + c];
    sd[tid] = s; __syncthreads();
    for (int st = 128; st > 0; st >>= 1) { if (tid < st) sd[tid] += sd[tid + st]; __syncthreads(); }
    const float total = sd[0];
    __syncthreads();
    float q = 0.f;
    for (int j = tid; j < npart; j += 256) q += Pq[j * C + c];
    sd[tid] = q; __syncthreads();
    for (int st = 128; st > 0; st >>= 1) { if (tid < st) sd[tid] += sd[tid + st]; __syncthreads(); }
    if (tid == 0) {
        const float mean = total * invn;
        const float var  = sd[0] * invn - mean * mean;
        const float scl  = gamma[c] * rsqrtf(var + 1e-5f);
        ss[c]     = scl;
        ss[C + c] = beta[c] - mean * scl;
    }
}

// ---------------- head: fused x-update + pool + MLP ----------------
__global__ __launch_bounds__(128)
void head_kernel(const float* __restrict__ x,
                 const float* __restrict__ summed,
                 const float* __restrict__ ss2,
                 const float* __restrict__ fc1W, const float* __restrict__ fc1b,
                 const float* __restrict__ fc2W, const float* __restrict__ fc2b,
                 const float* __restrict__ outW, const float* __restrict__ outb,
                 float* __restrict__ out)
{
    __shared__ float l0[AF], l1[HF], rr[2], hs[2][AF];
    const int b = blockIdx.x, tid = threadIdx.x;
    const int col = tid & 63, half = tid >> 6;
    {
        const float sc = ss2[col], sh = ss2[AF + col];
        float s = 0.f;
        #pragma unroll 4
        for (int a = half * 16; a < half * 16 + 16; ++a) {
            const size_t o = (size_t)(b * 32 + a) * AF + col;
            s += fsp(x[o] + fmaf(summed[o], sc, sh));
        }
        hs[half][col] = s;
    }
    __syncthreads();
    if (tid < AF) l0[tid] = fsp((hs[0][tid] + hs[1][tid]) * (1.f / 32.f));
    __syncthreads();
    float acc = fc1b[tid];
    #pragma unroll 4
    for (int k = 0; k < AF; ++k) acc = fmaf(l0[k], fc1W[k * HF + tid], acc);
    l1[tid] = fsp(acc);
    __syncthreads();
    acc = fc2b[tid];
    #pragma unroll 4
    for (int k = 0; k < HF; ++k) acc = fmaf(l1[k], fc2W[k * HF + tid], acc);
    float v = fsp(acc) * outW[tid];
    #pragma unroll
    for (int off = 32; off > 0; off >>= 1) v += __shfl_down(v, off, 64);
    if ((tid & 63) == 0) rr[tid >> 6] = v;
    __syncthreads();
    if (tid == 0) out[b] = rr[0] + rr[1] + outb[0];
}

extern "C" void kernel_launch(void* const* d_in, const int* in_sizes, int n_in,
                              void* d_out, int out_size, void* d_ws, size_t ws_size,
                              hipStream_t stream)
{
    const float* atom_fea = (const float*)d_in[0];
    const float* nbr_fea  = (const float*)d_in[1];
    const int*   nbr_idx  = (const int*)d_in[2];
    const float* emb_W  = (const float*)d_in[4];
    const float* emb_b  = (const float*)d_in[5];
    const float* conv_W = (const float*)d_in[6];
    const float* conv_b = (const float*)d_in[7];
    const float* bn1_g  = (const float*)d_in[8];
    const float* bn1_b  = (const float*)d_in[9];
    const float* bn2_g  = (const float*)d_in[10];
    const float* bn2_b  = (const float*)d_in[11];
    const float* fc1W   = (const float*)d_in[12];
    const float* fc1b   = (const float*)d_in[13];
    const float* fc2W   = (const float*)d_in[14];
    const float* fc2b   = (const float*)d_in[15];
    const float* outW   = (const float*)d_in[16];
    const float* outb   = (const float*)d_in[17];
    float* out = (float*)d_out;
    float* ws  = (float*)d_ws;

    float*    x_a    = ws;
    float*    x_b    = x_a + (size_t)NA * AF;
    float*    Sbuf   = x_b + (size_t)NA * AF;
    unsigned* Pb     = (unsigned*)(Sbuf + (size_t)NA * C2);   // NA x 64 uints (bf16 pairs)
    float*    summed = (float*)(Pb + (size_t)NA * 64);
    float*    P1s    = summed + (size_t)NA * AF;
    float*    P1q    = P1s + GRID_CONV * C2;
    float*    P2s    = P1q + GRID_CONV * C2;
    float*    P2q    = P2s + GRID_CONV * AF;
    float*    ss1    = P2q + GRID_CONV * AF;
    float*    ss2    = ss1 + 2 * C2;

    float* xcur = x_a;
    // layer 0 spx: embed + S/P
    spx_kernel<true><<<NA / 16, 256, 0, stream>>>(nullptr, nullptr, nullptr,
                                                  atom_fea, emb_W, emb_b,
                                                  conv_W, conv_b, xcur, Sbuf, Pb);
    for (int l = 0; l < NCONV; ++l) {
        conv6_kernel<0><<<GRID_CONV, 256, 0, stream>>>(nbr_fea, nbr_idx,
                                                       conv_W + (size_t)l * (C2 + NBR) * C2 + (size_t)C2 * C2,
                                                       Sbuf, Pb, nullptr, P1s, P1q,
                                                       nullptr, nullptr, nullptr);
        bn_finalize<<<C2, 256, 0, stream>>>(P1s, P1q, GRID_CONV, C2, 1.f / (float)NM,
                                            bn1_g + l * C2, bn1_b + l * C2, ss1);
        conv6_kernel<1><<<GRID_CONV, 256, 0, stream>>>(nbr_fea, nbr_idx,
                                                       conv_W + (size_t)l * (C2 + NBR) * C2 + (size_t)C2 * C2,
                                                       Sbuf, Pb, ss1, nullptr, nullptr,
                                                       summed, P2s, P2q);
        bn_finalize<<<AF, 256, 0, stream>>>(P2s, P2q, GRID_CONV, AF, 1.f / (float)NA,
                                            bn2_g + l * AF, bn2_b + l * AF, ss2);
        if (l < NCONV - 1) {
            float* xnext = (xcur == x_a) ? x_b : x_a;
            spx_kernel<false><<<NA / 16, 256, 0, stream>>>(xcur, summed, ss2,
                                                           nullptr, nullptr, nullptr,
                                                           conv_W + (size_t)(l + 1) * (C2 + NBR) * C2,
                                                           conv_b + (size_t)(l + 1) * C2,
                                                           xnext, Sbuf, Pb);
            xcur = xnext;
        }
    }
    head_kernel<<<BB, 128, 0, stream>>>(xcur, summed, ss2,
                                        fc1W, fc1b, fc2W, fc2b, outW, outb, out);
}

// Round 8
// 890.252 us; speedup vs baseline: 1.3414x; 1.3414x over previous
//
#include <hip/hip_runtime.h>
#include <cmath>

#define DEV __device__ __forceinline__

constexpr int NA    = 32768;          // atoms
constexpr int M     = 12;             // neighbors
constexpr int ORIG  = 92;
constexpr int NBR   = 41;
constexpr int AF    = 64;
constexpr int C2    = 128;            // 2*AF
constexpr int HF    = 128;
constexpr int NCONV = 3;
constexpr int NM    = NA * M;         // 393216
constexpr int BB    = 1024;           // crystals
constexpr int TA    = 4;              // atoms per tile
constexpr int RT    = TA * M;         // 48 rows per tile
constexpr int NTILES = NA / TA;       // 8192
constexpr int GRID_CONV = 4096;       // (tile, col-half) jobs: 2 halves
constexpr int TSTRIDE = GRID_CONV / 2;// 2048 tile stride per half
constexpr int WLD2  = 68;             // W2h row stride (64 cols + pad)
constexpr int ALD   = 44;             // A tile row stride (16B-aligned rows)

DEV float fsig(float x) { return __builtin_amdgcn_rcpf(1.f + __expf(-x)); }
DEV float fsp (float x) { return fmaxf(x, 0.f) + __logf(1.f + __expf(-fabsf(x))); }

DEV void fma4(float4& a, float s, const float4 w) {
    a.x = fmaf(s, w.x, a.x); a.y = fmaf(s, w.y, a.y);
    a.z = fmaf(s, w.z, a.z); a.w = fmaf(s, w.w, a.w);
}
DEV void fma2(float2& a, float s, const float2 w) {
    a.x = fmaf(s, w.x, a.x); a.y = fmaf(s, w.y, a.y);
}
DEV float comp4(const float4 v, int i) { return i == 0 ? v.x : i == 1 ? v.y : i == 2 ? v.z : v.w; }
DEV void add2(float2& a, const float2 b) { a.x += b.x; a.y += b.y; }
DEV void sqa2(float2& a, const float2 b) { a.x = fmaf(b.x, b.x, a.x); a.y = fmaf(b.y, b.y, a.y); }
DEV float2 shxor2(const float2 v, int m) {
    float2 r; r.x = __shfl_xor(v.x, m, 64); r.y = __shfl_xor(v.y, m, 64); return r;
}
DEV void bfly2(float2& v) {              // sum across lanes xor 16,32 (rid groups)
    float2 t = shxor2(v, 16); add2(v, t);
    t = shxor2(v, 32); add2(v, t);
}
DEV unsigned bf16pair(float a, float b) {   // RNE pack: low=a, high=b
    unsigned ua = __float_as_uint(a), ub = __float_as_uint(b);
    ua += 0x7fffu + ((ua >> 16) & 1u);
    ub += 0x7fffu + ((ub >> 16) & 1u);
    return (ua >> 16) | (ub & 0xffff0000u);
}
DEV float2 up2(unsigned u) {                // unpack 2 bf16 -> float2
    float2 r;
    r.x = __uint_as_float(u << 16);
    r.y = __uint_as_float(u & 0xffff0000u);
    return r;
}

// ---- spx: x-update (embed for layer0, softplus(x+bn2(summed)) otherwise)
//      fused with S = x@W[0:64]+b (fp32) and P = x@W[64:128] (packed bf16) ----
template<bool FIRST>
__global__ __launch_bounds__(256, 4)
void spx_kernel(const float* __restrict__ xin,
                const float* __restrict__ summed,
                const float* __restrict__ ss2,
                const float* __restrict__ atom_fea,
                const float* __restrict__ embW,
                const float* __restrict__ embb,
                const float* __restrict__ W,
                const float* __restrict__ bias,
                float* __restrict__ xout,
                float* __restrict__ S,
                unsigned* __restrict__ Pb)
{
    __shared__ float xs[16][AF];
    __shared__ float af[FIRST ? 16 * ORIG : 4];

    const int a0 = blockIdx.x * 16, tid = threadIdx.x;

    if (FIRST) {
        for (int i = tid; i < 16 * ORIG; i += 256) af[i] = atom_fea[(size_t)a0 * ORIG + i];
        __syncthreads();
        const int row = tid >> 4, c4 = (tid & 15) * 4;
        float4 acc = *(const float4*)(embb + c4);
        #pragma unroll 4
        for (int k = 0; k < ORIG; ++k)
            fma4(acc, af[row * ORIG + k], *(const float4*)(embW + k * AF + c4));
        *(float4*)&xs[row][c4] = acc;
        *(float4*)(xout + (size_t)(a0 + row) * AF + c4) = acc;
    } else {
        const int row = tid >> 4, c4 = (tid & 15) * 4;
        const size_t o = (size_t)(a0 + row) * AF + c4;
        const float4 xi = *(const float4*)(xin + o);
        const float4 sm = *(const float4*)(summed + o);
        const float4 sc = *(const float4*)(ss2 + c4);
        const float4 sh = *(const float4*)(ss2 + AF + c4);
        float4 ov;
        ov.x = fsp(xi.x + fmaf(sm.x, sc.x, sh.x));
        ov.y = fsp(xi.y + fmaf(sm.y, sc.y, sh.y));
        ov.z = fsp(xi.z + fmaf(sm.z, sc.z, sh.z));
        ov.w = fsp(xi.w + fmaf(sm.w, sc.w, sh.w));
        *(float4*)&xs[row][c4] = ov;
        *(float4*)(xout + o) = ov;
    }
    __syncthreads();

    const int cid = tid & 31, rid = tid >> 5;
    const int c0 = cid * 8, r0 = rid * 2;
    const bool isS = (c0 < 128);
    const int cc = c0 & 127;
    const float* Wb = W + (isS ? 0 : AF * C2) + cc;
    float4 a00, a01, a10, a11;
    if (isS) { a00 = *(const float4*)(bias + cc); a01 = *(const float4*)(bias + cc + 4); }
    else     { a00 = {0,0,0,0}; a01 = {0,0,0,0}; }
    a10 = a00; a11 = a01;
    for (int k = 0; k < AF; ++k) {
        const float4 w0 = *(const float4*)(Wb + k * C2);
        const float4 w1 = *(const float4*)(Wb + k * C2 + 4);
        const float x0 = xs[r0][k], x1 = xs[r0 + 1][k];
        fma4(a00, x0, w0); fma4(a01, x0, w1);
        fma4(a10, x1, w0); fma4(a11, x1, w1);
    }
    if (isS) {
        *(float4*)(S + (size_t)(a0 + r0) * C2 + cc)     = a00;
        *(float4*)(S + (size_t)(a0 + r0) * C2 + cc + 4) = a01;
        *(float4*)(S + (size_t)(a0 + r0 + 1) * C2 + cc)     = a10;
        *(float4*)(S + (size_t)(a0 + r0 + 1) * C2 + cc + 4) = a11;
    } else {
        uint4 u0, u1;
        u0.x = bf16pair(a00.x, a00.y); u0.y = bf16pair(a00.z, a00.w);
        u0.z = bf16pair(a01.x, a01.y); u0.w = bf16pair(a01.z, a01.w);
        u1.x = bf16pair(a10.x, a10.y); u1.y = bf16pair(a10.z, a10.w);
        u1.z = bf16pair(a11.x, a11.y); u1.w = bf16pair(a11.z, a11.w);
        *(uint4*)(Pb + (size_t)(a0 + r0) * 64 + cc / 2)     = u0;
        *(uint4*)(Pb + (size_t)(a0 + r0 + 1) * 64 + cc / 2) = u1;
    }
}

// ------- conv core, COLUMN-SPLIT: block (tile t, half ch) computes g columns
//   filter [ch*32, ch*32+32) and core [64+ch*32, 64+ch*32+32).
// Per thread: 3 rows x (2 filter + 2 core) cols -> 12 accumulator floats.
// No cross-GEMM register holds (R3-proven consume-at-init) -> fits 64 VGPRs.
// MODE 0: per-column sum/sumsq of g (BN1 partials, [block][64]).
// MODE 1: BN1-apply + gate + sum over M -> summed (32 cols); BN2 partials [block][32].
template<int MODE>
__global__ __launch_bounds__(256, 4)
void conv7_kernel(const float* __restrict__ nbr_fea,
                  const int* __restrict__ idx,
                  const float* __restrict__ W2,
                  const float* __restrict__ S,
                  const unsigned* __restrict__ Pb,
                  const float* __restrict__ ss1,
                  float* __restrict__ P1s, float* __restrict__ P1q,
                  float* __restrict__ summed,
                  float* __restrict__ P2s, float* __restrict__ P2q)
{
    __shared__ float W2h[NBR * WLD2];    // 11.2 KB (half the columns)
    __shared__ float sA[RT * ALD];       // 8.45 KB

    const int tid  = threadIdx.x;
    const int cid  = tid & 15;
    const int rid  = tid >> 4;
    const int ch   = blockIdx.x & 1;     // column half
    const int c2   = cid * 2;            // local col pair base (0..30)
    const int gf   = ch * 32 + c2;       // global filter col base
    const int gc   = 64 + gf;            // global core col base
    const int r0   = rid * 3;
    const int atom = tid >> 6;           // wave index == atom-in-tile

    // stage W2h: local col [0,32)=filter half, [32,64)=core half
    for (int i = tid; i < NBR * 16; i += 256) {
        const int k = i >> 4, q = i & 15;
        const int srcc = (q < 8) ? (ch * 32 + q * 4) : (64 + ch * 32 + (q - 8) * 4);
        *(float4*)&W2h[k * WLD2 + q * 4] = *(const float4*)(W2 + k * C2 + srcc);
    }

    // staging LDS offsets tile-invariant: element e -> sA[(e/41)*ALD + e%41]
    int soff[8];
    #pragma unroll
    for (int i = 0; i < 8; ++i) {
        const int e = tid + 256 * i;
        if (e < RT * NBR) {
            const int r = (int)(((unsigned)e * 102301u) >> 22);
            soff[i] = r * ALD + (e - r * NBR);
        } else soff[i] = -1;
    }

    float2 scf, scc, shf, shc;
    if (MODE == 1) {
        scf = *(const float2*)(ss1 + gf);       scc = *(const float2*)(ss1 + gc);
        shf = *(const float2*)(ss1 + C2 + gf);  shc = *(const float2*)(ss1 + C2 + gc);
    }

    float2 sum_f = {0,0}, sum_c = {0,0}, sq_f = {0,0}, sq_c = {0,0};   // MODE0
    float2 ts = {0,0}, tq = {0,0};                                      // MODE1

    for (int t = blockIdx.x >> 1; t < NTILES; t += TSTRIDE) {
        const int n0 = t * TA;
        const int ib = n0 * M + r0;
        const int j0 = idx[ib + 0];
        const int j1 = idx[ib + 1];
        const int j2 = idx[ib + 2];
        // gathers + S issued now, consumed at acc-init (short-lived)
        const unsigned u0f = Pb[(size_t)j0 * 64 + ch * 16 + cid];
        const unsigned u0c = Pb[(size_t)j0 * 64 + 32 + ch * 16 + cid];
        const unsigned u1f = Pb[(size_t)j1 * 64 + ch * 16 + cid];
        const unsigned u1c = Pb[(size_t)j1 * 64 + 32 + ch * 16 + cid];
        const unsigned u2f = Pb[(size_t)j2 * 64 + ch * 16 + cid];
        const unsigned u2c = Pb[(size_t)j2 * 64 + 32 + ch * 16 + cid];
        const float2 svf = *(const float2*)(S + (size_t)(n0 + atom) * C2 + gf);
        const float2 svc = *(const float2*)(S + (size_t)(n0 + atom) * C2 + gc);

        __syncthreads();                 // prev tile LDS fully consumed
        {
            const float* src = nbr_fea + (size_t)n0 * M * NBR;
            #pragma unroll
            for (int i = 0; i < 8; ++i) if (soff[i] >= 0) sA[soff[i]] = src[tid + 256 * i];
        }
        __syncthreads();

        // acc init = S + P[idx] (consumes gathers)
        float2 ef0 = svf, ec0 = svc, ef1 = svf, ec1 = svc, ef2 = svf, ec2 = svc;
        add2(ef0, up2(u0f)); add2(ec0, up2(u0c));
        add2(ef1, up2(u1f)); add2(ec1, up2(u1c));
        add2(ef2, up2(u2f)); add2(ec2, up2(u2c));

        // ---- E-GEMM: += nbr @ W2h, 3 rows x (2+2) cols ----
        const float4* A0 = (const float4*)(sA + (r0 + 0) * ALD);
        const float4* A1 = (const float4*)(sA + (r0 + 1) * ALD);
        const float4* A2 = (const float4*)(sA + (r0 + 2) * ALD);
        #pragma unroll 2
        for (int k4 = 0; k4 < 10; ++k4) {
            const float4 a0 = A0[k4], a1 = A1[k4], a2 = A2[k4];
            #pragma unroll
            for (int kk = 0; kk < 4; ++kk) {
                const int k = 4 * k4 + kk;
                const float2 wf = *(const float2*)(W2h + k * WLD2 + c2);
                const float2 wc = *(const float2*)(W2h + k * WLD2 + 32 + c2);
                fma2(ef0, comp4(a0, kk), wf); fma2(ec0, comp4(a0, kk), wc);
                fma2(ef1, comp4(a1, kk), wf); fma2(ec1, comp4(a1, kk), wc);
                fma2(ef2, comp4(a2, kk), wf); fma2(ec2, comp4(a2, kk), wc);
            }
        }
        {   // k = 40
            const float2 wf = *(const float2*)(W2h + 40 * WLD2 + c2);
            const float2 wc = *(const float2*)(W2h + 40 * WLD2 + 32 + c2);
            const float a0s = sA[(r0 + 0) * ALD + 40];
            const float a1s = sA[(r0 + 1) * ALD + 40];
            const float a2s = sA[(r0 + 2) * ALD + 40];
            fma2(ef0, a0s, wf); fma2(ec0, a0s, wc);
            fma2(ef1, a1s, wf); fma2(ec1, a1s, wc);
            fma2(ef2, a2s, wf); fma2(ec2, a2s, wc);
        }

        if (MODE == 0) {
            add2(sum_f, ef0); add2(sum_f, ef1); add2(sum_f, ef2);
            add2(sum_c, ec0); add2(sum_c, ec1); add2(sum_c, ec2);
            sqa2(sq_f, ef0);  sqa2(sq_f, ef1);  sqa2(sq_f, ef2);
            sqa2(sq_c, ec0);  sqa2(sq_c, ec1);  sqa2(sq_c, ec2);
        } else {
            float2 part = {0, 0};
            #pragma unroll
            for (int j = 0; j < 3; ++j) {
                const float2 gfv = (j == 0) ? ef0 : (j == 1) ? ef1 : ef2;
                const float2 gcv = (j == 0) ? ec0 : (j == 1) ? ec1 : ec2;
                float2 nf, nc;
                nf.x = fmaf(gfv.x, scf.x, shf.x); nf.y = fmaf(gfv.y, scf.y, shf.y);
                nc.x = fmaf(gcv.x, scc.x, shc.x); nc.y = fmaf(gcv.y, scc.y, shc.y);
                part.x = fmaf(fsig(nf.x), fsp(nc.x), part.x);
                part.y = fmaf(fsig(nf.y), fsp(nc.y), part.y);
            }
            bfly2(part);                 // sum over the wave's 4 rid groups (12 rows)
            if ((tid & 48) == 0) {
                *(float2*)(summed + (size_t)(n0 + atom) * AF + ch * 32 + c2) = part;
                add2(ts, part);
                sqa2(tq, part);
            }
        }
    }

    if (MODE == 0) {   // block reduce: bfly over rids, then across atoms via sA
        bfly2(sum_f); bfly2(sum_c); bfly2(sq_f); bfly2(sq_c);
        __syncthreads();                 // sA free (all tiles done)
        if ((tid & 48) == 0) {
            *(float2*)&sA[atom * 64 + c2]            = sum_f;
            *(float2*)&sA[atom * 64 + 32 + c2]       = sum_c;
            *(float2*)&sA[256 + atom * 64 + c2]      = sq_f;
            *(float2*)&sA[256 + atom * 64 + 32 + c2] = sq_c;
        }
        __syncthreads();
        if (tid < 64) {
            P1s[(size_t)blockIdx.x * 64 + tid] = sA[tid] + sA[64 + tid] + sA[128 + tid] + sA[192 + tid];
            P1q[(size_t)blockIdx.x * 64 + tid] = sA[256 + tid] + sA[256 + 64 + tid]
                                               + sA[256 + 128 + tid] + sA[256 + 192 + tid];
        }
    } else {           // BN2 partials: [block][32]
        __syncthreads();
        if ((tid & 48) == 0) {
            *(float2*)&sA[atom * 32 + c2]       = ts;
            *(float2*)&sA[128 + atom * 32 + c2] = tq;
        }
        __syncthreads();
        if (tid < 32) {
            P2s[(size_t)blockIdx.x * 32 + tid] = sA[tid] + sA[32 + tid] + sA[64 + tid] + sA[96 + tid];
            P2q[(size_t)blockIdx.x * 32 + tid] = sA[128 + tid] + sA[128 + 32 + tid]
                                               + sA[128 + 64 + tid] + sA[128 + 96 + tid];
        }
    }
}

// ---- BN finalize over half-column partials: col c's partials live in blocks
//      with (block & 1) == ch(c), at local index lc(c). rowlen: 64 (BN1) / 32 (BN2).
__global__ __launch_bounds__(256)
void bn_finalize(const float* __restrict__ Ps, const float* __restrict__ Pq,
                 int rowlen, float invn,
                 const float* __restrict__ gamma, const float* __restrict__ beta,
                 float* __restrict__ ss, int Ctot)
{
    __shared__ float sd[256];
    const int c = blockIdx.x, tid = threadIdx.x;
    const int ch = (c >> 5) & 1;
    const int lc = (c & 31) + ((c >= 64) ? 32 : 0);
    float s = 0.f;
    for (int i = tid; i < TSTRIDE; i += 256) s += Ps[(size_t)(ch + 2 * i) * rowlen + lc];
    sd[tid] = s; __syncthreads();
    for (int st = 128; st > 0; st >>= 1) { if (tid < st) sd[tid] += sd[tid + st]; __syncthreads(); }
    const float total = sd[0];
    __syncthreads();
    float q = 0.f;
    for (int i = tid; i < TSTRIDE; i += 256) q += Pq[(size_t)(ch + 2 * i) * rowlen + lc];
    sd[tid] = q; __syncthreads();
    for (int st = 128; st > 0; st >>= 1) { if (tid < st) sd[tid] += sd[tid + st]; __syncthreads(); }
    if (tid == 0) {
        const float mean = total * invn;
        const float var  = sd[0] * invn - mean * mean;
        const float scl  = gamma[c] * rsqrtf(var + 1e-5f);
        ss[c]        = scl;
        ss[Ctot + c] = beta[c] - mean * scl;
    }
}

// ---------------- head: fused x-update + pool + MLP ----------------
__global__ __launch_bounds__(128)
void head_kernel(const float* __restrict__ x,
                 const float* __restrict__ summed,
                 const float* __restrict__ ss2,
                 const float* __restrict__ fc1W, const float* __restrict__ fc1b,
                 const float* __restrict__ fc2W, const float* __restrict__ fc2b,
                 const float* __restrict__ outW, const float* __restrict__ outb,
                 float* __restrict__ out)
{
    __shared__ float l0[AF], l1[HF], rr[2], hs[2][AF];
    const int b = blockIdx.x, tid = threadIdx.x;
    const int col = tid & 63, half = tid >> 6;
    {
        const float sc = ss2[col], sh = ss2[AF + col];
        float s = 0.f;
        #pragma unroll 4
        for (int a = half * 16; a < half * 16 + 16; ++a) {
            const size_t o = (size_t)(b * 32 + a) * AF + col;
            s += fsp(x[o] + fmaf(summed[o], sc, sh));
        }
        hs[half][col] = s;
    }
    __syncthreads();
    if (tid < AF) l0[tid] = fsp((hs[0][tid] + hs[1][tid]) * (1.f / 32.f));
    __syncthreads();
    float acc = fc1b[tid];
    #pragma unroll 4
    for (int k = 0; k < AF; ++k) acc = fmaf(l0[k], fc1W[k * HF + tid], acc);
    l1[tid] = fsp(acc);
    __syncthreads();
    acc = fc2b[tid];
    #pragma unroll 4
    for (int k = 0; k < HF; ++k) acc = fmaf(l1[k], fc2W[k * HF + tid], acc);
    float v = fsp(acc) * outW[tid];
    #pragma unroll
    for (int off = 32; off > 0; off >>= 1) v += __shfl_down(v, off, 64);
    if ((tid & 63) == 0) rr[tid >> 6] = v;
    __syncthreads();
    if (tid == 0) out[b] = rr[0] + rr[1] + outb[0];
}

extern "C" void kernel_launch(void* const* d_in, const int* in_sizes, int n_in,
                              void* d_out, int out_size, void* d_ws, size_t ws_size,
                              hipStream_t stream)
{
    const float* atom_fea = (const float*)d_in[0];
    const float* nbr_fea  = (const float*)d_in[1];
    const int*   nbr_idx  = (const int*)d_in[2];
    const float* emb_W  = (const float*)d_in[4];
    const float* emb_b  = (const float*)d_in[5];
    const float* conv_W = (const float*)d_in[6];
    const float* conv_b = (const float*)d_in[7];
    const float* bn1_g  = (const float*)d_in[8];
    const float* bn1_b  = (const float*)d_in[9];
    const float* bn2_g  = (const float*)d_in[10];
    const float* bn2_b  = (const float*)d_in[11];
    const float* fc1W   = (const float*)d_in[12];
    const float* fc1b   = (const float*)d_in[13];
    const float* fc2W   = (const float*)d_in[14];
    const float* fc2b   = (const float*)d_in[15];
    const float* outW   = (const float*)d_in[16];
    const float* outb   = (const float*)d_in[17];
    float* out = (float*)d_out;
    float* ws  = (float*)d_ws;

    float*    x_a    = ws;
    float*    x_b    = x_a + (size_t)NA * AF;
    float*    Sbuf   = x_b + (size_t)NA * AF;
    unsigned* Pb     = (unsigned*)(Sbuf + (size_t)NA * C2);   // NA x 64 uints (bf16 pairs)
    float*    summed = (float*)(Pb + (size_t)NA * 64);
    float*    P1s    = summed + (size_t)NA * AF;
    float*    P1q    = P1s + (size_t)GRID_CONV * 64;
    float*    P2s    = P1q + (size_t)GRID_CONV * 64;
    float*    P2q    = P2s + (size_t)GRID_CONV * 32;
    float*    ss1    = P2q + (size_t)GRID_CONV * 32;
    float*    ss2    = ss1 + 2 * C2;

    float* xcur = x_a;
    spx_kernel<true><<<NA / 16, 256, 0, stream>>>(nullptr, nullptr, nullptr,
                                                  atom_fea, emb_W, emb_b,
                                                  conv_W, conv_b, xcur, Sbuf, Pb);
    for (int l = 0; l < NCONV; ++l) {
        const float* W2 = conv_W + (size_t)l * (C2 + NBR) * C2 + (size_t)C2 * C2;
        conv7_kernel<0><<<GRID_CONV, 256, 0, stream>>>(nbr_fea, nbr_idx, W2,
                                                       Sbuf, Pb, nullptr, P1s, P1q,
                                                       nullptr, nullptr, nullptr);
        bn_finalize<<<C2, 256, 0, stream>>>(P1s, P1q, 64, 1.f / (float)NM,
                                            bn1_g + l * C2, bn1_b + l * C2, ss1, C2);
        conv7_kernel<1><<<GRID_CONV, 256, 0, stream>>>(nbr_fea, nbr_idx, W2,
                                                       Sbuf, Pb, ss1, nullptr, nullptr,
                                                       summed, P2s, P2q);
        bn_finalize<<<AF, 256, 0, stream>>>(P2s, P2q, 32, 1.f / (float)NA,
                                            bn2_g + l * AF, bn2_b + l * AF, ss2, AF);
        if (l < NCONV - 1) {
            float* xnext = (xcur == x_a) ? x_b : x_a;
            spx_kernel<false><<<NA / 16, 256, 0, stream>>>(xcur, summed, ss2,
                                                           nullptr, nullptr, nullptr,
                                                           conv_W + (size_t)(l + 1) * (C2 + NBR) * C2,
                                                           conv_b + (size_t)(l + 1) * C2,
                                                           xnext, Sbuf, Pb);
            xcur = xnext;
        }
    }
    head_kernel<<<BB, 128, 0, stream>>>(xcur, summed, ss2,
                                        fc1W, fc1b, fc2W, fc2b, outW, outb, out);
}

// Round 9
// 694.807 us; speedup vs baseline: 1.7187x; 1.2813x over previous
//
#include <hip/hip_runtime.h>
#include <cmath>

#define DEV __device__ __forceinline__

constexpr int NA    = 32768;          // atoms
constexpr int M     = 12;             // neighbors
constexpr int ORIG  = 92;
constexpr int NBR   = 41;
constexpr int AF    = 64;
constexpr int C2    = 128;            // 2*AF
constexpr int HF    = 128;
constexpr int NCONV = 3;
constexpr int NM    = NA * M;         // 393216
constexpr int BB    = 1024;           // crystals
constexpr int TA    = 4;              // atoms per tile
constexpr int RT    = TA * M;         // 48 rows per tile
constexpr int NTILES = NA / TA;       // 8192
constexpr int GRID_CONV = 4096;       // (tile, col-half) jobs: 2 halves
constexpr int TSTRIDE = GRID_CONV / 2;// 2048 tile stride per half
constexpr int GRID_APPLY = 2048;
constexpr int WLD2  = 68;             // W2h row stride (64 cols + pad)
constexpr int ALD   = 44;             // A tile row stride (16B-aligned rows)

DEV float fsig(float x) { return __builtin_amdgcn_rcpf(1.f + __expf(-x)); }
DEV float fsp (float x) { return fmaxf(x, 0.f) + __logf(1.f + __expf(-fabsf(x))); }

DEV void fma4(float4& a, float s, const float4 w) {
    a.x = fmaf(s, w.x, a.x); a.y = fmaf(s, w.y, a.y);
    a.z = fmaf(s, w.z, a.z); a.w = fmaf(s, w.w, a.w);
}
DEV void fma2(float2& a, float s, const float2 w) {
    a.x = fmaf(s, w.x, a.x); a.y = fmaf(s, w.y, a.y);
}
DEV float comp4(const float4 v, int i) { return i == 0 ? v.x : i == 1 ? v.y : i == 2 ? v.z : v.w; }
DEV void add2(float2& a, const float2 b) { a.x += b.x; a.y += b.y; }
DEV void sqa2(float2& a, const float2 b) { a.x = fmaf(b.x, b.x, a.x); a.y = fmaf(b.y, b.y, a.y); }
DEV float2 shxor2(const float2 v, int m) {
    float2 r; r.x = __shfl_xor(v.x, m, 64); r.y = __shfl_xor(v.y, m, 64); return r;
}
DEV void bfly2(float2& v) {              // sum across lanes xor 16,32 (rid groups)
    float2 t = shxor2(v, 16); add2(v, t);
    t = shxor2(v, 32); add2(v, t);
}
DEV unsigned bf16pair(float a, float b) {   // RNE pack: low=a, high=b
    unsigned ua = __float_as_uint(a), ub = __float_as_uint(b);
    ua += 0x7fffu + ((ua >> 16) & 1u);
    ub += 0x7fffu + ((ub >> 16) & 1u);
    return (ua >> 16) | (ub & 0xffff0000u);
}
DEV float2 up2(unsigned u) {                // unpack 2 bf16 -> float2
    float2 r;
    r.x = __uint_as_float(u << 16);
    r.y = __uint_as_float(u & 0xffff0000u);
    return r;
}

// ---- spx: x-update (embed for layer0, softplus(x+bn2(summed)) otherwise)
//      fused with S = x@W[0:64]+b (fp32) and P = x@W[64:128] (packed bf16) ----
template<bool FIRST>
__global__ __launch_bounds__(256, 4)
void spx_kernel(const float* __restrict__ xin,
                const float* __restrict__ summed,
                const float* __restrict__ ss2,
                const float* __restrict__ atom_fea,
                const float* __restrict__ embW,
                const float* __restrict__ embb,
                const float* __restrict__ W,
                const float* __restrict__ bias,
                float* __restrict__ xout,
                float* __restrict__ S,
                unsigned* __restrict__ Pb)
{
    __shared__ float xs[16][AF];
    __shared__ float af[FIRST ? 16 * ORIG : 4];

    const int a0 = blockIdx.x * 16, tid = threadIdx.x;

    if (FIRST) {
        for (int i = tid; i < 16 * ORIG; i += 256) af[i] = atom_fea[(size_t)a0 * ORIG + i];
        __syncthreads();
        const int row = tid >> 4, c4 = (tid & 15) * 4;
        float4 acc = *(const float4*)(embb + c4);
        #pragma unroll 4
        for (int k = 0; k < ORIG; ++k)
            fma4(acc, af[row * ORIG + k], *(const float4*)(embW + k * AF + c4));
        *(float4*)&xs[row][c4] = acc;
        *(float4*)(xout + (size_t)(a0 + row) * AF + c4) = acc;
    } else {
        const int row = tid >> 4, c4 = (tid & 15) * 4;
        const size_t o = (size_t)(a0 + row) * AF + c4;
        const float4 xi = *(const float4*)(xin + o);
        const float4 sm = *(const float4*)(summed + o);
        const float4 sc = *(const float4*)(ss2 + c4);
        const float4 sh = *(const float4*)(ss2 + AF + c4);
        float4 ov;
        ov.x = fsp(xi.x + fmaf(sm.x, sc.x, sh.x));
        ov.y = fsp(xi.y + fmaf(sm.y, sc.y, sh.y));
        ov.z = fsp(xi.z + fmaf(sm.z, sc.z, sh.z));
        ov.w = fsp(xi.w + fmaf(sm.w, sc.w, sh.w));
        *(float4*)&xs[row][c4] = ov;
        *(float4*)(xout + o) = ov;
    }
    __syncthreads();

    const int cid = tid & 31, rid = tid >> 5;
    const int c0 = cid * 8, r0 = rid * 2;
    const bool isS = (c0 < 128);
    const int cc = c0 & 127;
    const float* Wb = W + (isS ? 0 : AF * C2) + cc;
    float4 a00, a01, a10, a11;
    if (isS) { a00 = *(const float4*)(bias + cc); a01 = *(const float4*)(bias + cc + 4); }
    else     { a00 = {0,0,0,0}; a01 = {0,0,0,0}; }
    a10 = a00; a11 = a01;
    for (int k = 0; k < AF; ++k) {
        const float4 w0 = *(const float4*)(Wb + k * C2);
        const float4 w1 = *(const float4*)(Wb + k * C2 + 4);
        const float x0 = xs[r0][k], x1 = xs[r0 + 1][k];
        fma4(a00, x0, w0); fma4(a01, x0, w1);
        fma4(a10, x1, w0); fma4(a11, x1, w1);
    }
    if (isS) {
        *(float4*)(S + (size_t)(a0 + r0) * C2 + cc)     = a00;
        *(float4*)(S + (size_t)(a0 + r0) * C2 + cc + 4) = a01;
        *(float4*)(S + (size_t)(a0 + r0 + 1) * C2 + cc)     = a10;
        *(float4*)(S + (size_t)(a0 + r0 + 1) * C2 + cc + 4) = a11;
    } else {
        uint4 u0, u1;
        u0.x = bf16pair(a00.x, a00.y); u0.y = bf16pair(a00.z, a00.w);
        u0.z = bf16pair(a01.x, a01.y); u0.w = bf16pair(a01.z, a01.w);
        u1.x = bf16pair(a10.x, a10.y); u1.y = bf16pair(a10.z, a10.w);
        u1.z = bf16pair(a11.x, a11.y); u1.w = bf16pair(a11.z, a11.w);
        *(uint4*)(Pb + (size_t)(a0 + r0) * 64 + cc / 2)     = u0;
        *(uint4*)(Pb + (size_t)(a0 + r0 + 1) * 64 + cc / 2) = u1;
    }
}

// ------- conv stats pass, COLUMN-SPLIT (R8 structure, spill-free at 60 VGPR):
//   g[n,m] = S[n] + P[idx[n,m]] + nbr[n,m]@W2 for cols ch*32..+32 & 64+ch*32..+32.
//   Accumulates BN1 sum/sumsq partials AND writes g as packed bf16 pairs
//   (row-major [edge][64 uints]) so the apply pass never recomputes the GEMM.
__global__ __launch_bounds__(256, 4)
void conv8_kernel(const float* __restrict__ nbr_fea,
                  const int* __restrict__ idx,
                  const float* __restrict__ W2,
                  const float* __restrict__ S,
                  const unsigned* __restrict__ Pb,
                  float* __restrict__ P1s, float* __restrict__ P1q,
                  unsigned* __restrict__ gout)
{
    __shared__ float W2h[NBR * WLD2];    // 11.2 KB (half the columns)
    __shared__ float sA[RT * ALD];       // 8.45 KB

    const int tid  = threadIdx.x;
    const int cid  = tid & 15;
    const int rid  = tid >> 4;
    const int ch   = blockIdx.x & 1;     // column half
    const int c2   = cid * 2;            // local col pair base (0..30)
    const int gf   = ch * 32 + c2;       // global filter col base
    const int gc   = 64 + gf;            // global core col base
    const int r0   = rid * 3;
    const int atom = tid >> 6;           // wave index == atom-in-tile

    // stage W2h: local col [0,32)=filter half, [32,64)=core half
    for (int i = tid; i < NBR * 16; i += 256) {
        const int k = i >> 4, q = i & 15;
        const int srcc = (q < 8) ? (ch * 32 + q * 4) : (64 + ch * 32 + (q - 8) * 4);
        *(float4*)&W2h[k * WLD2 + q * 4] = *(const float4*)(W2 + k * C2 + srcc);
    }

    // staging LDS offsets tile-invariant: element e -> sA[(e/41)*ALD + e%41]
    int soff[8];
    #pragma unroll
    for (int i = 0; i < 8; ++i) {
        const int e = tid + 256 * i;
        if (e < RT * NBR) {
            const int r = (int)(((unsigned)e * 102301u) >> 22);
            soff[i] = r * ALD + (e - r * NBR);
        } else soff[i] = -1;
    }

    float2 sum_f = {0,0}, sum_c = {0,0}, sq_f = {0,0}, sq_c = {0,0};

    for (int t = blockIdx.x >> 1; t < NTILES; t += TSTRIDE) {
        const int n0 = t * TA;
        const int ib = n0 * M + r0;
        const int j0 = idx[ib + 0];
        const int j1 = idx[ib + 1];
        const int j2 = idx[ib + 2];
        // gathers + S issued now, consumed at acc-init (short-lived)
        const unsigned u0f = Pb[(size_t)j0 * 64 + ch * 16 + cid];
        const unsigned u0c = Pb[(size_t)j0 * 64 + 32 + ch * 16 + cid];
        const unsigned u1f = Pb[(size_t)j1 * 64 + ch * 16 + cid];
        const unsigned u1c = Pb[(size_t)j1 * 64 + 32 + ch * 16 + cid];
        const unsigned u2f = Pb[(size_t)j2 * 64 + ch * 16 + cid];
        const unsigned u2c = Pb[(size_t)j2 * 64 + 32 + ch * 16 + cid];
        const float2 svf = *(const float2*)(S + (size_t)(n0 + atom) * C2 + gf);
        const float2 svc = *(const float2*)(S + (size_t)(n0 + atom) * C2 + gc);

        __syncthreads();                 // prev tile LDS fully consumed
        {
            const float* src = nbr_fea + (size_t)n0 * M * NBR;
            #pragma unroll
            for (int i = 0; i < 8; ++i) if (soff[i] >= 0) sA[soff[i]] = src[tid + 256 * i];
        }
        __syncthreads();

        // acc init = S + P[idx] (consumes gathers)
        float2 ef0 = svf, ec0 = svc, ef1 = svf, ec1 = svc, ef2 = svf, ec2 = svc;
        add2(ef0, up2(u0f)); add2(ec0, up2(u0c));
        add2(ef1, up2(u1f)); add2(ec1, up2(u1c));
        add2(ef2, up2(u2f)); add2(ec2, up2(u2c));

        // ---- E-GEMM: += nbr @ W2h, 3 rows x (2+2) cols ----
        const float4* A0 = (const float4*)(sA + (r0 + 0) * ALD);
        const float4* A1 = (const float4*)(sA + (r0 + 1) * ALD);
        const float4* A2 = (const float4*)(sA + (r0 + 2) * ALD);
        #pragma unroll 2
        for (int k4 = 0; k4 < 10; ++k4) {
            const float4 a0 = A0[k4], a1 = A1[k4], a2 = A2[k4];
            #pragma unroll
            for (int kk = 0; kk < 4; ++kk) {
                const int k = 4 * k4 + kk;
                const float2 wf = *(const float2*)(W2h + k * WLD2 + c2);
                const float2 wc = *(const float2*)(W2h + k * WLD2 + 32 + c2);
                fma2(ef0, comp4(a0, kk), wf); fma2(ec0, comp4(a0, kk), wc);
                fma2(ef1, comp4(a1, kk), wf); fma2(ec1, comp4(a1, kk), wc);
                fma2(ef2, comp4(a2, kk), wf); fma2(ec2, comp4(a2, kk), wc);
            }
        }
        {   // k = 40
            const float2 wf = *(const float2*)(W2h + 40 * WLD2 + c2);
            const float2 wc = *(const float2*)(W2h + 40 * WLD2 + 32 + c2);
            const float a0s = sA[(r0 + 0) * ALD + 40];
            const float a1s = sA[(r0 + 1) * ALD + 40];
            const float a2s = sA[(r0 + 2) * ALD + 40];
            fma2(ef0, a0s, wf); fma2(ec0, a0s, wc);
            fma2(ef1, a1s, wf); fma2(ec1, a1s, wc);
            fma2(ef2, a2s, wf); fma2(ec2, a2s, wc);
        }

        // ---- write g (bf16 pairs, row-major [edge][64 uints]) ----
        {
            const size_t row0 = (size_t)(n0 * M + r0) * 64 + ch * 16 + cid;
            gout[row0]       = bf16pair(ef0.x, ef0.y);
            gout[row0 + 32]  = bf16pair(ec0.x, ec0.y);
            gout[row0 + 64]  = bf16pair(ef1.x, ef1.y);
            gout[row0 + 96]  = bf16pair(ec1.x, ec1.y);
            gout[row0 + 128] = bf16pair(ef2.x, ef2.y);
            gout[row0 + 160] = bf16pair(ec2.x, ec2.y);
        }

        // ---- BN1 stats partials ----
        add2(sum_f, ef0); add2(sum_f, ef1); add2(sum_f, ef2);
        add2(sum_c, ec0); add2(sum_c, ec1); add2(sum_c, ec2);
        sqa2(sq_f, ef0);  sqa2(sq_f, ef1);  sqa2(sq_f, ef2);
        sqa2(sq_c, ec0);  sqa2(sq_c, ec1);  sqa2(sq_c, ec2);
    }

    // block reduce: bfly over rids, then across atoms via sA
    bfly2(sum_f); bfly2(sum_c); bfly2(sq_f); bfly2(sq_c);
    __syncthreads();                 // sA free (all tiles done)
    if ((tid & 48) == 0) {
        *(float2*)&sA[atom * 64 + c2]            = sum_f;
        *(float2*)&sA[atom * 64 + 32 + c2]       = sum_c;
        *(float2*)&sA[256 + atom * 64 + c2]      = sq_f;
        *(float2*)&sA[256 + atom * 64 + 32 + c2] = sq_c;
    }
    __syncthreads();
    if (tid < 64) {
        P1s[(size_t)blockIdx.x * 64 + tid] = sA[tid] + sA[64 + tid] + sA[128 + tid] + sA[192 + tid];
        P1q[(size_t)blockIdx.x * 64 + tid] = sA[256 + tid] + sA[256 + 64 + tid]
                                           + sA[256 + 128 + tid] + sA[256 + 192 + tid];
    }
}

// ---- apply pass: read g (bf16), BN1, sigmoid*softplus gate, sum over M ->
//      summed; fused BN2 partial stats. Sequential reads, memory-bound. ----
__global__ __launch_bounds__(256)
void apply_g_kernel(const unsigned* __restrict__ g,
                    const float* __restrict__ ss1,
                    float* __restrict__ summed,
                    float* __restrict__ P2s, float* __restrict__ P2q)
{
    const int tid = threadIdx.x;
    const int al  = tid >> 5;            // 8 atoms per block
    const int c2  = tid & 31;            // col pair
    const int cA  = 2 * c2;
    const float2 scf = *(const float2*)(ss1 + cA);
    const float2 scc = *(const float2*)(ss1 + 64 + cA);
    const float2 shf = *(const float2*)(ss1 + C2 + cA);
    const float2 shc = *(const float2*)(ss1 + C2 + 64 + cA);
    float2 ts = {0.f, 0.f}, tq = {0.f, 0.f};

    for (int grp = blockIdx.x; grp < NA / 8; grp += gridDim.x) {
        const int a = grp * 8 + al;
        const unsigned* gr = g + (size_t)a * M * 64 + c2;
        float2 acc = {0.f, 0.f};
        #pragma unroll
        for (int m = 0; m < M; ++m) {
            const unsigned uf = gr[m * 64];
            const unsigned us = gr[m * 64 + 32];
            const float2 f = up2(uf);
            const float2 s = up2(us);
            acc.x = fmaf(fsig(fmaf(f.x, scf.x, shf.x)), fsp(fmaf(s.x, scc.x, shc.x)), acc.x);
            acc.y = fmaf(fsig(fmaf(f.y, scf.y, shf.y)), fsp(fmaf(s.y, scc.y, shc.y)), acc.y);
        }
        *(float2*)(summed + (size_t)a * AF + cA) = acc;
        ts.x += acc.x; ts.y += acc.y;
        tq.x = fmaf(acc.x, acc.x, tq.x); tq.y = fmaf(acc.y, acc.y, tq.y);
    }

    __shared__ float2 rs[8][32], rq[8][32];
    rs[al][c2] = ts; rq[al][c2] = tq;
    __syncthreads();
    if (tid < 32) {
        float2 s = rs[0][tid], q = rq[0][tid];
        #pragma unroll
        for (int a = 1; a < 8; ++a) {
            s.x += rs[a][tid].x; s.y += rs[a][tid].y;
            q.x += rq[a][tid].x; q.y += rq[a][tid].y;
        }
        *(float2*)(P2s + (size_t)blockIdx.x * AF + 2 * tid) = s;
        *(float2*)(P2q + (size_t)blockIdx.x * AF + 2 * tid) = q;
    }
}

// ---- BN1 finalize over half-column partials: col c's partials live in blocks
//      with (block & 1) == ch(c), at local index lc(c). rowlen = 64.
__global__ __launch_bounds__(256)
void bn_finalize_half(const float* __restrict__ Ps, const float* __restrict__ Pq,
                      int rowlen, float invn,
                      const float* __restrict__ gamma, const float* __restrict__ beta,
                      float* __restrict__ ss, int Ctot)
{
    __shared__ float sd[256];
    const int c = blockIdx.x, tid = threadIdx.x;
    const int ch = (c >> 5) & 1;
    const int lc = (c & 31) + ((c >= 64) ? 32 : 0);
    float s = 0.f;
    for (int i = tid; i < TSTRIDE; i += 256) s += Ps[(size_t)(ch + 2 * i) * rowlen + lc];
    sd[tid] = s; __syncthreads();
    for (int st = 128; st > 0; st >>= 1) { if (tid < st) sd[tid] += sd[tid + st]; __syncthreads(); }
    const float total = sd[0];
    __syncthreads();
    float q = 0.f;
    for (int i = tid; i < TSTRIDE; i += 256) q += Pq[(size_t)(ch + 2 * i) * rowlen + lc];
    sd[tid] = q; __syncthreads();
    for (int st = 128; st > 0; st >>= 1) { if (tid < st) sd[tid] += sd[tid + st]; __syncthreads(); }
    if (tid == 0) {
        const float mean = total * invn;
        const float var  = sd[0] * invn - mean * mean;
        const float scl  = gamma[c] * rsqrtf(var + 1e-5f);
        ss[c]        = scl;
        ss[Ctot + c] = beta[c] - mean * scl;
    }
}

// ---- plain BN finalize (BN2): partials [npart][C] ----
__global__ __launch_bounds__(256)
void bn_finalize_plain(const float* __restrict__ Ps, const float* __restrict__ Pq,
                       int npart, int C, float invn,
                       const float* __restrict__ gamma, const float* __restrict__ beta,
                       float* __restrict__ ss)
{
    __shared__ float sd[256];
    const int c = blockIdx.x, tid = threadIdx.x;
    float s = 0.f;
    for (int j = tid; j < npart; j += 256) s += Ps[(size_t)j * C + c];
    sd[tid] = s; __syncthreads();
    for (int st = 128; st > 0; st >>= 1) { if (tid < st) sd[tid] += sd[tid + st]; __syncthreads(); }
    const float total = sd[0];
    __syncthreads();
    float q = 0.f;
    for (int j = tid; j < npart; j += 256) q += Pq[(size_t)j * C + c];
    sd[tid] = q; __syncthreads();
    for (int st = 128; st > 0; st >>= 1) { if (tid < st) sd[tid] += sd[tid + st]; __syncthreads(); }
    if (tid == 0) {
        const float mean = total * invn;
        const float var  = sd[0] * invn - mean * mean;
        const float scl  = gamma[c] * rsqrtf(var + 1e-5f);
        ss[c]     = scl;
        ss[C + c] = beta[c] - mean * scl;
    }
}

// ---------------- head: fused x-update + pool + MLP ----------------
__global__ __launch_bounds__(128)
void head_kernel(const float* __restrict__ x,
                 const float* __restrict__ summed,
                 const float* __restrict__ ss2,
                 const float* __restrict__ fc1W, const float* __restrict__ fc1b,
                 const float* __restrict__ fc2W, const float* __restrict__ fc2b,
                 const float* __restrict__ outW, const float* __restrict__ outb,
                 float* __restrict__ out)
{
    __shared__ float l0[AF], l1[HF], rr[2], hs[2][AF];
    const int b = blockIdx.x, tid = threadIdx.x;
    const int col = tid & 63, half = tid >> 6;
    {
        const float sc = ss2[col], sh = ss2[AF + col];
        float s = 0.f;
        #pragma unroll 4
        for (int a = half * 16; a < half * 16 + 16; ++a) {
            const size_t o = (size_t)(b * 32 + a) * AF + col;
            s += fsp(x[o] + fmaf(summed[o], sc, sh));
        }
        hs[half][col] = s;
    }
    __syncthreads();
    if (tid < AF) l0[tid] = fsp((hs[0][tid] + hs[1][tid]) * (1.f / 32.f));
    __syncthreads();
    float acc = fc1b[tid];
    #pragma unroll 4
    for (int k = 0; k < AF; ++k) acc = fmaf(l0[k], fc1W[k * HF + tid], acc);
    l1[tid] = fsp(acc);
    __syncthreads();
    acc = fc2b[tid];
    #pragma unroll 4
    for (int k = 0; k < HF; ++k) acc = fmaf(l1[k], fc2W[k * HF + tid], acc);
    float v = fsp(acc) * outW[tid];
    #pragma unroll
    for (int off = 32; off > 0; off >>= 1) v += __shfl_down(v, off, 64);
    if ((tid & 63) == 0) rr[tid >> 6] = v;
    __syncthreads();
    if (tid == 0) out[b] = rr[0] + rr[1] + outb[0];
}

extern "C" void kernel_launch(void* const* d_in, const int* in_sizes, int n_in,
                              void* d_out, int out_size, void* d_ws, size_t ws_size,
                              hipStream_t stream)
{
    const float* atom_fea = (const float*)d_in[0];
    const float* nbr_fea  = (const float*)d_in[1];
    const int*   nbr_idx  = (const int*)d_in[2];
    const float* emb_W  = (const float*)d_in[4];
    const float* emb_b  = (const float*)d_in[5];
    const float* conv_W = (const float*)d_in[6];
    const float* conv_b = (const float*)d_in[7];
    const float* bn1_g  = (const float*)d_in[8];
    const float* bn1_b  = (const float*)d_in[9];
    const float* bn2_g  = (const float*)d_in[10];
    const float* bn2_b  = (const float*)d_in[11];
    const float* fc1W   = (const float*)d_in[12];
    const float* fc1b   = (const float*)d_in[13];
    const float* fc2W   = (const float*)d_in[14];
    const float* fc2b   = (const float*)d_in[15];
    const float* outW   = (const float*)d_in[16];
    const float* outb   = (const float*)d_in[17];
    float* out = (float*)d_out;
    float* ws  = (float*)d_ws;

    // workspace (~154 MB; R4 proved >= ~162 MB exists)
    float*    x_a    = ws;
    float*    x_b    = x_a + (size_t)NA * AF;
    float*    Sbuf   = x_b + (size_t)NA * AF;
    unsigned* Pb     = (unsigned*)(Sbuf + (size_t)NA * C2);   // NA x 64 uints (bf16 pairs)
    float*    summed = (float*)(Pb + (size_t)NA * 64);
    float*    P1s    = summed + (size_t)NA * AF;
    float*    P1q    = P1s + (size_t)GRID_CONV * 64;
    float*    P2s    = P1q + (size_t)GRID_CONV * 64;
    float*    P2q    = P2s + (size_t)GRID_APPLY * AF;
    float*    ss1    = P2q + (size_t)GRID_APPLY * AF;
    float*    ss2    = ss1 + 2 * C2;
    unsigned* gbuf   = (unsigned*)(ss2 + 2 * AF);             // NM x 64 uints (bf16 pairs)

    float* xcur = x_a;
    spx_kernel<true><<<NA / 16, 256, 0, stream>>>(nullptr, nullptr, nullptr,
                                                  atom_fea, emb_W, emb_b,
                                                  conv_W, conv_b, xcur, Sbuf, Pb);
    for (int l = 0; l < NCONV; ++l) {
        const float* W2 = conv_W + (size_t)l * (C2 + NBR) * C2 + (size_t)C2 * C2;
        conv8_kernel<<<GRID_CONV, 256, 0, stream>>>(nbr_fea, nbr_idx, W2,
                                                    Sbuf, Pb, P1s, P1q, gbuf);
        bn_finalize_half<<<C2, 256, 0, stream>>>(P1s, P1q, 64, 1.f / (float)NM,
                                                 bn1_g + l * C2, bn1_b + l * C2, ss1, C2);
        apply_g_kernel<<<GRID_APPLY, 256, 0, stream>>>(gbuf, ss1, summed, P2s, P2q);
        bn_finalize_plain<<<AF, 256, 0, stream>>>(P2s, P2q, GRID_APPLY, AF, 1.f / (float)NA,
                                                  bn2_g + l * AF, bn2_b + l * AF, ss2);
        if (l < NCONV - 1) {
            float* xnext = (xcur == x_a) ? x_b : x_a;
            spx_kernel<false><<<NA / 16, 256, 0, stream>>>(xcur, summed, ss2,
                                                           nullptr, nullptr, nullptr,
                                                           conv_W + (size_t)(l + 1) * (C2 + NBR) * C2,
                                                           conv_b + (size_t)(l + 1) * C2,
                                                           xnext, Sbuf, Pb);
            xcur = xnext;
        }
    }
    head_kernel<<<BB, 128, 0, stream>>>(xcur, summed, ss2,
                                        fc1W, fc1b, fc2W, fc2b, outW, outb, out);
}